// Round 10
// baseline (363.356 us; speedup 1.0000x reference)
//
#include <hip/hip_runtime.h>
#include <cstdint>
#include <cstddef>

#define BB 32
#define NN 24564
#define CC 81
#define CM1 80
#define KTOP 100
#define MAXDET 100
#define CBINS 28          // quarter-octave bins over score in (0.0078, 1]
#define CSHIFT 21
#define BASEBITS 0x3C000000u
#define SPECBITS 0x3D400000u   // bin-10 boundary = 0.046875f
#define SPECPF   0.0468281f    // SPEC * 0.999 proxy prefilter
#define CAPB 25           // per-block per-class spec slots
#define BPI 96            // blocks per image, 256 rows each
#define CAPF (BPI * CAPB) // 2400 slots per (b,c)
#define HWORDS (CM1 * (CBINS / 2))        // 1120 packed u32 words
#define ARRC 4096         // nms LDS sort capacity
#define FCH 8
#define FCHN 1000
#define FPAD 1024

typedef unsigned long long ull;
typedef unsigned int uint;
typedef float floatx4 __attribute__((ext_vector_type(4)));
typedef floatx4 uf4 __attribute__((aligned(4)));   // rows are only 4B-aligned

// ---- pass 1: register rows, exact softmax stats, proxy LDS hist, slotted spec collect ----
// NO zero-init required anywhere: every global word consumed later is written here unconditionally.
__global__ __launch_bounds__(256) void softmax_hist_kernel(const float* __restrict__ conf,
                                                           uint* __restrict__ histg,
                                                           float2* __restrict__ mxs,
                                                           ull* __restrict__ cand,
                                                           uint* __restrict__ cnts) {
    __shared__ uint h[HWORDS];           // 4480 B
    __shared__ ull  sbuf[CM1 * CAPB];    // 16000 B
    __shared__ uint scnt[CM1];           // 320 B
    int tid = threadIdx.x;
    for (int i = tid; i < HWORDS; i += 256) h[i] = 0u;
    if (tid < CM1) scnt[tid] = 0u;
    __syncthreads();

    int b = blockIdx.x / BPI, j = blockIdx.x % BPI;
    int n = j * 256 + tid;
    if (n < NN) {
        const float* row = conf + ((size_t)b * NN + n) * CC;
        const uf4* row4 = reinterpret_cast<const uf4*>(row);
        float r[CC];
        #pragma unroll
        for (int q = 0; q < 20; ++q) {
            floatx4 v = row4[q];
            r[4 * q] = v.x; r[4 * q + 1] = v.y; r[4 * q + 2] = v.z; r[4 * q + 3] = v.w;
        }
        r[80] = row[80];

        float mx = r[0];
        #pragma unroll
        for (int c = 1; c < CC; ++c) mx = fmaxf(mx, r[c]);   // max: order-independent, exact

        float s = 0.f;                                        // exact sequential sum, c = 0..80
        #pragma unroll
        for (int c = 0; c < CC; ++c) {
            r[c] = expf(__fsub_rn(r[c], mx));
            s = __fadd_rn(s, r[c]);
        }
        mxs[(size_t)b * NN + n] = make_float2(mx, s);

        float rcp = __builtin_amdgcn_rcpf(s);
        uint nn = (uint)n;
        #pragma unroll
        for (int c = 1; c < CC; ++c) {
            float p = __fmul_rn(r[c], rcp);
            if (p <= 0.0099990f) continue;            // certainly <= 0.01 (rcp err ~1e-7)
            uint bits;
            if (p >= 0.0100010f) bits = __float_as_uint(p);   // proxy bin; cut margin covers +-1 bin
            else {
                float sc = __fdiv_rn(r[c], s);
                if (!(sc > 0.01f)) continue;
                bits = __float_as_uint(sc);
            }
            uint bin = (bits - BASEBITS) >> CSHIFT;
            if (bin >= CBINS) bin = CBINS - 1;
            atomicAdd(&h[(c - 1) * (CBINS / 2) + (bin >> 1)], (bin & 1) ? 65536u : 1u);

            // speculative collect: exact bits >= SPEC boundary, LDS-buffered
            if (p > SPECPF) {
                float sc2 = __fdiv_rn(r[c], s);        // exact score bits
                uint eb = __float_as_uint(sc2);
                if (eb >= SPECBITS) {
                    uint pp = atomicAdd(&scnt[c - 1], 1u);
                    if (pp < CAPB) sbuf[(c - 1) * CAPB + pp] = (((ull)(~eb)) << 32) | nn;
                }
            }
        }
    }
    __syncthreads();

    uint* dst = histg + (size_t)blockIdx.x * HWORDS;
    for (int i = tid; i < HWORDS; i += 256) dst[i] = h[i];

    // flush: raw count (always written) + candidates to this block's fixed slots
    if (tid < CM1) {
        uint cnt = scnt[tid];
        cnts[((size_t)(b * BPI + j)) * CM1 + tid] = cnt;
        uint nstore = cnt > CAPB ? CAPB : cnt;
        ull* dstc = cand + ((size_t)(b * CM1 + tid)) * CAPF + j * CAPB;
        for (uint i = 0; i < nstore; ++i) dstc[i] = sbuf[tid * CAPB + i];
    }
}

// ---- pass 2: sum packed partials; tight rank-100 cut; spec sufficiency from slot counts ----
__global__ __launch_bounds__(128) void cut_kernel(const uint* __restrict__ histg,
                                                  const uint* __restrict__ cnts,
                                                  uint* __restrict__ cuts,
                                                  uint* __restrict__ flags) {
    int bc = blockIdx.x;
    int b = bc / CM1, c = bc % CM1;
    __shared__ uint sh[CBINS];
    __shared__ uint sm[BPI], so[BPI];
    int t = threadIdx.x;
    if (t < CBINS / 2) {
        uint sum = 0;   // halves <= 96*256 fit u16: packed adds never carry
        for (int jj = 0; jj < BPI; ++jj)
            sum += histg[(size_t)(b * BPI + jj) * HWORDS + c * (CBINS / 2) + t];
        sh[2 * t]     = sum & 0xFFFFu;
        sh[2 * t + 1] = sum >> 16;
    }
    if (t < BPI) {
        uint v = cnts[((size_t)(b * BPI + t)) * CM1 + c];
        sm[t] = v > CAPB ? CAPB : v;
        so[t] = v > CAPB ? 1u : 0u;
    }
    __syncthreads();
    if (t == 0) {
        uint total = 0;
        for (int i = 0; i < CBINS; ++i) total += sh[i];
        int Kt = (int)(total < KTOP ? total : KTOP);
        uint cutv = 0xFFFFFFFFu;
        uint flag = 0u;
        if (Kt > 0) {
            uint cum = 0; int bb2 = 0;
            for (int i = CBINS - 1; i >= 0; --i) {
                cum += sh[i];
                if (cum >= (uint)Kt) { bb2 = i; break; }
            }
            uint cum_m = cum + ((bb2 > 0) ? sh[bb2 - 1] : 0u);
            uint cutbin;
            if (bb2 > 0 && cum_m <= ARRC / 2) cutbin = (uint)(bb2 - 1);  // margin bin (proxy safety)
            else if (cum <= ARRC / 2)         cutbin = (uint)bb2;
            else                              cutbin = (uint)(bb2 + 1);
            cutv = BASEBITS + (cutbin << CSHIFT);
            uint specTotal = 0, anyOvf = 0;
            for (int jj = 0; jj < BPI; ++jj) { specTotal += sm[jj]; anyOvf |= so[jj]; }
            // sufficiency: no truncation anywhere and >= Kt items above SPEC boundary
            flag = (anyOvf == 0u && specTotal >= (uint)Kt) ? 0u : 1u;
        }
        cuts[bc] = cutv;
        flags[bc] = flag;
    }
}

// ---- pass 3 (rare): exact column re-collect for flagged classes; writes compact list + fbcnt ----
__global__ __launch_bounds__(256) void fallback_kernel(const float* __restrict__ conf,
                                                       const float2* __restrict__ mxs,
                                                       const uint* __restrict__ cuts,
                                                       const uint* __restrict__ flags,
                                                       ull* __restrict__ cand,
                                                       uint* __restrict__ fbcnt) {
    int bc = blockIdx.x;
    if (flags[bc] == 0u) return;
    int b = bc / CM1, c = bc % CM1 + 1;
    uint cutv = cuts[bc];
    __shared__ uint lcnt;
    int tid = threadIdx.x;
    if (tid == 0) lcnt = 0u;
    __syncthreads();
    for (int n = tid; n < NN; n += 256) {
        float x = conf[((size_t)b * NN + n) * CC + c];
        float2 ms = mxs[(size_t)b * NN + n];
        float e = expf(__fsub_rn(x, ms.x));
        float sc = __fdiv_rn(e, ms.y);
        if (sc > 0.01f) {
            uint bits = __float_as_uint(sc);
            if (bits >= cutv) {
                uint p = atomicAdd(&lcnt, 1u);
                if (p < CAPF)
                    cand[(size_t)bc * CAPF + p] = (((ull)(~bits)) << 32) | (uint)n;
            }
        }
    }
    __syncthreads();
    if (tid == 0) fbcnt[bc] = (lcnt < CAPF) ? lcnt : CAPF;
}

// ---- pass 4: per-(b,c) gather (slots or compact) + filter, sort, fused decode, greedy NMS ----
__global__ __launch_bounds__(256) void nms_kernel(const ull* __restrict__ cand,
                                                  const uint* __restrict__ cnts,
                                                  const uint* __restrict__ fbcnt,
                                                  const uint* __restrict__ flags,
                                                  const uint* __restrict__ cuts,
                                                  const float* __restrict__ loc,
                                                  const float* __restrict__ priors,
                                                  float* __restrict__ nms_scores,
                                                  float* __restrict__ nms_boxes) {
    int bc = blockIdx.x;
    int bimg = bc / CM1, c = bc % CM1;
    __shared__ ull arr[ARRC];                 // 32 KB
    __shared__ float bx[KTOP][4];
    __shared__ float sv[KTOP];
    __shared__ ull mlo[KTOP], mhi[KTOP];
    __shared__ ull keeplo, keephi;
    __shared__ int scnt;

    int tid = threadIdx.x;
    if (tid == 0) scnt = 0;
    __syncthreads();

    uint cutv = cuts[bc];
    const ull* crow = cand + (size_t)bc * CAPF;
    if (flags[bc] == 0u) {
        // spec slot layout: 96 blocks x <=25 candidates
        for (int jj = tid; jj < BPI; jj += 256) {
            uint cnt = cnts[((size_t)(bimg * BPI + jj)) * CM1 + c];
            if (cnt > CAPB) cnt = CAPB;
            const ull* src = crow + jj * CAPB;
            for (uint i = 0; i < cnt; ++i) {
                ull k = src[i];
                uint bits = ~(uint)(k >> 32);
                if (bits >= cutv) { int p = atomicAdd(&scnt, 1); arr[p] = k; }
            }
        }
    } else {
        int cc0 = (int)fbcnt[bc]; if (cc0 > CAPF) cc0 = CAPF;
        for (int i = tid; i < cc0; i += 256) {
            ull k = crow[i];
            uint bits = ~(uint)(k >> 32);
            if (bits >= cutv) { int p = atomicAdd(&scnt, 1); arr[p] = k; }
        }
    }
    __syncthreads();
    int cc = scnt;
    int S = 1; while (S < cc) S <<= 1; if (S < 2) S = 2;
    for (int i = cc + tid; i < S; i += 256) arr[i] = ~0ull;
    __syncthreads();

    for (int k = 2; k <= S; k <<= 1) {
        for (int jj = k >> 1; jj > 0; jj >>= 1) {
            for (int i = tid; i < S; i += 256) {
                int ixj = i ^ jj;
                if (ixj > i) {
                    ull a = arr[i], b2 = arr[ixj];
                    bool up = ((i & k) == 0);
                    if ((a > b2) == up) { arr[i] = b2; arr[ixj] = a; }
                }
            }
            __syncthreads();
        }
    }

    if (tid < KTOP) {
        float val = 0.f; uint n = 0;
        if (tid < cc) {
            ull kk = arr[tid];
            val = __uint_as_float(~(uint)(kk >> 32));
            n = (uint)(kk & 0xFFFFFFFFu);
        }
        sv[tid] = val;
        float4 l = reinterpret_cast<const float4*>(loc)[(size_t)bimg * NN + n];
        float4 p = reinterpret_cast<const float4*>(priors)[n];
        float cx = __fadd_rn(__fmul_rn(__fmul_rn(l.x, 0.1f), p.z), p.x);
        float cy = __fadd_rn(__fmul_rn(__fmul_rn(l.y, 0.1f), p.w), p.y);
        float w  = __fmul_rn(expf(__fmul_rn(l.z, 0.2f)), p.z);
        float h  = __fmul_rn(expf(__fmul_rn(l.w, 0.2f)), p.w);
        bx[tid][0] = __fsub_rn(cx, __fmul_rn(w, 0.5f));
        bx[tid][1] = __fsub_rn(cy, __fmul_rn(h, 0.5f));
        bx[tid][2] = __fadd_rn(cx, __fmul_rn(w, 0.5f));
        bx[tid][3] = __fadd_rn(cy, __fmul_rn(h, 0.5f));
    }
    __syncthreads();

    if (tid < KTOP) {
        float x1 = bx[tid][0], y1 = bx[tid][1], x2 = bx[tid][2], y2 = bx[tid][3];
        float ai = __fmul_rn(fmaxf(__fsub_rn(x2, x1), 0.f), fmaxf(__fsub_rn(y2, y1), 0.f));
        ull lo = 0, hi = 0;
        for (int jj = 0; jj < KTOP; ++jj) {
            float jx1 = bx[jj][0], jy1 = bx[jj][1], jx2 = bx[jj][2], jy2 = bx[jj][3];
            float iw = fmaxf(__fsub_rn(fminf(x2, jx2), fmaxf(x1, jx1)), 0.f);
            float ih = fmaxf(__fsub_rn(fminf(y2, jy2), fmaxf(y1, jy1)), 0.f);
            float inter = __fmul_rn(iw, ih);
            float aj = __fmul_rn(fmaxf(__fsub_rn(jx2, jx1), 0.f), fmaxf(__fsub_rn(jy2, jy1), 0.f));
            float denom = __fadd_rn(__fsub_rn(__fadd_rn(ai, aj), inter), 1e-8f);
            float iou = __fdiv_rn(inter, denom);
            if (iou > 0.45f) { if (jj < 64) lo |= (1ull << jj); else hi |= (1ull << (jj - 64)); }
        }
        mlo[tid] = lo; mhi[tid] = hi;
    }
    __syncthreads();

    if (tid == 0) {
        ull klo = 0, khi = 0;
        for (int i = 0; i < KTOP; ++i) {
            ull sup = (mlo[i] & klo) | (mhi[i] & khi);
            bool kp = (sv[i] > 0.f) && (sup == 0ull);
            if (kp) { if (i < 64) klo |= (1ull << i); else khi |= (1ull << (i - 64)); }
        }
        keeplo = klo; keephi = khi;
    }
    __syncthreads();

    if (tid < KTOP) {
        bool kp = (tid < 64) ? ((keeplo >> tid) & 1ull) : ((keephi >> (tid - 64)) & 1ull);
        size_t obase = (size_t)bc * KTOP + tid;
        nms_scores[obase] = kp ? sv[tid] : 0.f;
        float4 o; o.x = bx[tid][0]; o.y = bx[tid][1]; o.z = bx[tid][2]; o.w = bx[tid][3];
        reinterpret_cast<float4*>(nms_boxes)[obase] = o;
    }
}

// ---- final top-100, stage A: per-(image,chunk) top-100 of 1000 ----
__global__ __launch_bounds__(256) void final_partial_kernel(const float* __restrict__ nms_scores,
                                                            ull* __restrict__ fkeys) {
    int blk = blockIdx.x;             // b*FCH + ch
    int b = blk / FCH, ch = blk % FCH;
    __shared__ ull arr[FPAD];         // 8 KB
    int tid = threadIdx.x;
    const float* srow = nms_scores + (size_t)b * (CM1 * KTOP) + ch * FCHN;
    for (int i = tid; i < FPAD; i += 256) {
        ull key;
        if (i < FCHN) {
            float s = srow[i];
            uint bits = (s > 0.f) ? __float_as_uint(s) : 0u;
            key = (((ull)(~bits)) << 32) | (uint)(ch * FCHN + i);   // global per-image idx
        } else key = ~0ull;
        arr[i] = key;
    }
    __syncthreads();
    for (int k = 2; k <= FPAD; k <<= 1) {
        for (int jj = k >> 1; jj > 0; jj >>= 1) {
            for (int i = tid; i < FPAD; i += 256) {
                int ixj = i ^ jj;
                if (ixj > i) {
                    ull a = arr[i], b2 = arr[ixj];
                    bool up = ((i & k) == 0);
                    if ((a > b2) == up) { arr[i] = b2; arr[ixj] = a; }
                }
            }
            __syncthreads();
        }
    }
    if (tid < KTOP)
        fkeys[(size_t)b * (FCH * KTOP) + ch * KTOP + tid] = arr[tid];
}

// ---- final top-100, stage B: merge 8x100 -> exact top-100, gather ----
__global__ __launch_bounds__(256) void final_merge_kernel(const ull* __restrict__ fkeys,
                                                          const float* __restrict__ nms_boxes,
                                                          float* __restrict__ out) {
    int b = blockIdx.x;
    __shared__ ull arr[FPAD];         // 8 KB
    int tid = threadIdx.x;
    const ull* krow = fkeys + (size_t)b * (FCH * KTOP);
    for (int i = tid; i < FPAD; i += 256)
        arr[i] = (i < FCH * KTOP) ? krow[i] : ~0ull;
    __syncthreads();
    for (int k = 2; k <= FPAD; k <<= 1) {
        for (int jj = k >> 1; jj > 0; jj >>= 1) {
            for (int i = tid; i < FPAD; i += 256) {
                int ixj = i ^ jj;
                if (ixj > i) {
                    ull a = arr[i], b2 = arr[ixj];
                    bool up = ((i & k) == 0);
                    if ((a > b2) == up) { arr[i] = b2; arr[ixj] = a; }
                }
            }
            __syncthreads();
        }
    }
    if (tid < MAXDET) {
        ull kk = arr[tid];
        uint hb = (uint)(kk >> 32);
        uint idx = (uint)(kk & 0xFFFFFFFFu);
        float val = __uint_as_float(~hb);     // zeros decode to 0.0f
        float4 b4 = reinterpret_cast<const float4*>(nms_boxes)[(size_t)b * (CM1 * KTOP) + idx];
        reinterpret_cast<float4*>(out)[(size_t)b * MAXDET + tid] = b4;
        out[BB * MAXDET * 4 + b * MAXDET + tid] = val;
        out[BB * MAXDET * 5 + b * MAXDET + tid] = (float)(idx / KTOP + 1);
    }
}

extern "C" void kernel_launch(void* const* d_in, const int* in_sizes, int n_in,
                              void* d_out, int out_size, void* d_ws, size_t ws_size,
                              hipStream_t stream) {
    const float* loc    = (const float*)d_in[0];
    const float* conf   = (const float*)d_in[1];
    const float* priors = (const float*)d_in[2];
    float* out = (float*)d_out;

    // workspace layout (16B-aligned chunks); NO buffer requires zero-init.
    char* ws = (char*)d_ws;
    float* nms_scores = (float*)ws;                                        // 1.02 MB
    float* nms_boxes  = nms_scores + (size_t)BB * CM1 * KTOP;              // 4.1 MB
    ull*   cand       = (ull*)(nms_boxes + (size_t)BB * CM1 * KTOP * 4);   // 2560*2400*8 = 47.2 MB
    float2* mxs       = (float2*)(cand + (size_t)BB * CM1 * CAPF);         // 6.3 MB
    ull*   fkeys      = (ull*)(mxs + (size_t)BB * NN);                     // 0.2 MB
    uint*  histg      = (uint*)(fkeys + (size_t)BB * FCH * KTOP);          // 13.8 MB
    uint*  cnts       = histg + (size_t)BB * BPI * HWORDS;                 // 32*96*80*4 = 1.0 MB
    uint*  cuts       = cnts + (size_t)BB * BPI * CM1;                     // 2560
    uint*  flags      = cuts + (size_t)BB * CM1;                           // 2560
    uint*  fbcnt      = flags + (size_t)BB * CM1;                          // 2560

    softmax_hist_kernel<<<BB * BPI, 256, 0, stream>>>(conf, histg, mxs, cand, cnts);
    cut_kernel<<<BB * CM1, 128, 0, stream>>>(histg, cnts, cuts, flags);
    fallback_kernel<<<BB * CM1, 256, 0, stream>>>(conf, mxs, cuts, flags, cand, fbcnt);
    nms_kernel<<<BB * CM1, 256, 0, stream>>>(cand, cnts, fbcnt, flags, cuts, loc, priors, nms_scores, nms_boxes);
    final_partial_kernel<<<BB * FCH, 256, 0, stream>>>(nms_scores, fkeys);
    final_merge_kernel<<<BB, 256, 0, stream>>>(fkeys, nms_boxes, out);
}

// Round 11
// 301.982 us; speedup vs baseline: 1.2032x; 1.2032x over previous
//
#include <hip/hip_runtime.h>
#include <cstdint>
#include <cstddef>

#define BB 32
#define NN 24564
#define CC 81
#define CM1 80
#define KTOP 100
#define MAXDET 100
#define CBINS 28          // quarter-octave bins over score in (0.0078, 1]
#define CSHIFT 21
#define BASEBITS 0x3C000000u
#define SPECBITS 0x3D400000u   // bin-10 boundary = 0.046875f
#define SPECPF   0.0468281f    // SPEC * 0.999 proxy prefilter
#define CAP2 2048
#define CAPB 25           // per-block per-class spec buffer
#define BPI 96            // blocks per image, 256 rows each
#define HWORDS (CM1 * (CBINS / 2))        // 1120 packed u32 words
#define FCH 8
#define FCHN 1000
#define FPAD 1024

typedef unsigned long long ull;
typedef unsigned int uint;
typedef float floatx4 __attribute__((ext_vector_type(4)));
typedef floatx4 uf4 __attribute__((aligned(4)));   // rows are only 4B-aligned

// ---- pass 0: zero the 5120 counter words ourselves (hipMemsetAsync's fill path costs ~147us) ----
__global__ __launch_bounds__(256) void zero_kernel(uint* __restrict__ p, int nwords) {
    int i = blockIdx.x * 256 + threadIdx.x;
    if (i < nwords) p[i] = 0u;
}

// ---- pass 1: register rows, exact softmax stats, proxy LDS hist, LDS-buffered spec collect ----
__global__ __launch_bounds__(256) void softmax_hist_kernel(const float* __restrict__ conf,
                                                           uint* __restrict__ histg,
                                                           float2* __restrict__ mxs,
                                                           ull* __restrict__ cand,
                                                           uint* __restrict__ ccnt,
                                                           uint* __restrict__ ovf) {
    __shared__ uint h[HWORDS];           // 4480 B
    __shared__ ull  sbuf[CM1 * CAPB];    // 16000 B
    __shared__ uint scnt[CM1];           // 320 B
    int tid = threadIdx.x;
    for (int i = tid; i < HWORDS; i += 256) h[i] = 0u;
    if (tid < CM1) scnt[tid] = 0u;
    __syncthreads();

    int b = blockIdx.x / BPI, j = blockIdx.x % BPI;
    int n = j * 256 + tid;
    if (n < NN) {
        const float* row = conf + ((size_t)b * NN + n) * CC;
        const uf4* row4 = reinterpret_cast<const uf4*>(row);
        float r[CC];
        #pragma unroll
        for (int q = 0; q < 20; ++q) {
            floatx4 v = row4[q];
            r[4 * q] = v.x; r[4 * q + 1] = v.y; r[4 * q + 2] = v.z; r[4 * q + 3] = v.w;
        }
        r[80] = row[80];

        float mx = r[0];
        #pragma unroll
        for (int c = 1; c < CC; ++c) mx = fmaxf(mx, r[c]);   // max: order-independent, exact

        float s = 0.f;                                        // exact sequential sum, c = 0..80
        #pragma unroll
        for (int c = 0; c < CC; ++c) {
            r[c] = expf(__fsub_rn(r[c], mx));
            s = __fadd_rn(s, r[c]);
        }
        mxs[(size_t)b * NN + n] = make_float2(mx, s);

        float rcp = __builtin_amdgcn_rcpf(s);
        uint nn = (uint)n;
        #pragma unroll
        for (int c = 1; c < CC; ++c) {
            float p = __fmul_rn(r[c], rcp);
            if (p <= 0.0099990f) continue;            // certainly <= 0.01 (rcp err ~1e-7)
            uint bits;
            if (p >= 0.0100010f) bits = __float_as_uint(p);   // proxy bin; cut margin covers +-1 bin
            else {
                float sc = __fdiv_rn(r[c], s);
                if (!(sc > 0.01f)) continue;
                bits = __float_as_uint(sc);
            }
            uint bin = (bits - BASEBITS) >> CSHIFT;
            if (bin >= CBINS) bin = CBINS - 1;
            atomicAdd(&h[(c - 1) * (CBINS / 2) + (bin >> 1)], (bin & 1) ? 65536u : 1u);

            // speculative collect: exact bits >= SPEC boundary, buffered in LDS (no global RT)
            if (p > SPECPF) {
                float sc2 = __fdiv_rn(r[c], s);        // exact score bits
                uint eb = __float_as_uint(sc2);
                if (eb >= SPECBITS) {
                    uint pp = atomicAdd(&scnt[c - 1], 1u);
                    if (pp < CAPB) sbuf[(c - 1) * CAPB + pp] = (((ull)(~eb)) << 32) | nn;
                }
            }
        }
    }
    __syncthreads();

    uint* dst = histg + (size_t)blockIdx.x * HWORDS;
    for (int i = tid; i < HWORDS; i += 256) dst[i] = h[i];

    // flush spec buffers: one global atomic per class per block, then coalesced copy
    if (tid < CM1) {
        uint cnt = scnt[tid];
        if (cnt) {
            uint nstore = cnt > CAPB ? CAPB : cnt;
            int bc = b * CM1 + tid;
            uint base = atomicAdd(ccnt + bc, nstore);
            if (cnt > CAPB || base + nstore > CAP2) ovf[bc] = 1u;
            uint lim = base + nstore; if (lim > CAP2) lim = CAP2;
            for (uint i = 0; base + i < lim; ++i)
                cand[(size_t)bc * CAP2 + base + i] = sbuf[tid * CAPB + i];
        }
    }
}

// ---- pass 2: sum packed partials; tight rank-100 cut; decide spec-OK vs fallback ----
__global__ __launch_bounds__(64) void cut_kernel(const uint* __restrict__ histg,
                                                 const uint* __restrict__ ccnt,
                                                 const uint* __restrict__ ovf,
                                                 uint* __restrict__ cuts,
                                                 uint* __restrict__ flags) {
    int bc = blockIdx.x;
    int b = bc / CM1, c = bc % CM1;
    __shared__ uint sh[CBINS];
    int t = threadIdx.x;
    if (t < CBINS / 2) {
        uint sum = 0;   // halves <= 96*256 fit u16: packed adds never carry
        for (int jj = 0; jj < BPI; ++jj)
            sum += histg[(size_t)(b * BPI + jj) * HWORDS + c * (CBINS / 2) + t];
        sh[2 * t]     = sum & 0xFFFFu;
        sh[2 * t + 1] = sum >> 16;
    }
    __syncthreads();
    if (t == 0) {
        uint total = 0;
        for (int i = 0; i < CBINS; ++i) total += sh[i];
        int Kt = (int)(total < KTOP ? total : KTOP);
        uint cutv = 0xFFFFFFFFu;
        uint flag = 0u;
        if (Kt > 0) {
            uint cum = 0; int bb2 = 0;
            for (int i = CBINS - 1; i >= 0; --i) {
                cum += sh[i];
                if (cum >= (uint)Kt) { bb2 = i; break; }
            }
            uint cum_m = cum + ((bb2 > 0) ? sh[bb2 - 1] : 0u);
            uint cutbin;
            if (bb2 > 0 && cum_m <= CAP2) cutbin = (uint)(bb2 - 1);  // margin bin (proxy safety)
            else if (cum <= CAP2)         cutbin = (uint)bb2;
            else                          cutbin = (uint)(bb2 + 1);
            cutv = BASEBITS + (cutbin << CSHIFT);
            // spec list sufficient iff never truncated and holds >= Kt items (all >= SPECBITS kept)
            uint specCount = ccnt[bc];
            flag = (ovf[bc] == 0u && specCount >= (uint)Kt) ? 0u : 1u;
        }
        cuts[bc] = cutv;
        flags[bc] = flag;
    }
}

// ---- pass 3 (rare): exact column re-collect for flagged classes ----
__global__ __launch_bounds__(256) void fallback_kernel(const float* __restrict__ conf,
                                                       const float2* __restrict__ mxs,
                                                       const uint* __restrict__ cuts,
                                                       const uint* __restrict__ flags,
                                                       ull* __restrict__ cand,
                                                       uint* __restrict__ ccnt) {
    int bc = blockIdx.x;
    if (flags[bc] == 0u) return;
    int b = bc / CM1, c = bc % CM1 + 1;
    uint cutv = cuts[bc];
    __shared__ uint lcnt;
    int tid = threadIdx.x;
    if (tid == 0) lcnt = 0u;
    __syncthreads();
    for (int n = tid; n < NN; n += 256) {
        float x = conf[((size_t)b * NN + n) * CC + c];
        float2 ms = mxs[(size_t)b * NN + n];
        float e = expf(__fsub_rn(x, ms.x));
        float sc = __fdiv_rn(e, ms.y);
        if (sc > 0.01f) {
            uint bits = __float_as_uint(sc);
            if (bits >= cutv) {
                uint p = atomicAdd(&lcnt, 1u);
                if (p < CAP2)
                    cand[(size_t)bc * CAP2 + p] = (((ull)(~bits)) << 32) | (uint)n;
            }
        }
    }
    __syncthreads();
    if (tid == 0) ccnt[bc] = (lcnt < CAP2) ? lcnt : CAP2;
}

// ---- pass 4: per-(b,c) filter+compact, sort, fused box decode, greedy NMS ----
__global__ __launch_bounds__(256) void nms_kernel(const ull* __restrict__ cand,
                                                  const uint* __restrict__ ccnt,
                                                  const uint* __restrict__ cuts,
                                                  const float* __restrict__ loc,
                                                  const float* __restrict__ priors,
                                                  float* __restrict__ nms_scores,
                                                  float* __restrict__ nms_boxes) {
    int bc = blockIdx.x;
    int bimg = bc / CM1;
    __shared__ ull arr[CAP2];                 // 16 KB
    __shared__ float bx[KTOP][4];
    __shared__ float sv[KTOP];
    __shared__ ull mlo[KTOP], mhi[KTOP];
    __shared__ ull keeplo, keephi;
    __shared__ int scnt;

    int tid = threadIdx.x;
    if (tid == 0) scnt = 0;
    __syncthreads();

    int cc0 = (int)ccnt[bc]; if (cc0 > CAP2) cc0 = CAP2;
    uint cutv = cuts[bc];
    const ull* crow = cand + (size_t)bc * CAP2;
    for (int i = tid; i < cc0; i += 256) {
        ull k = crow[i];
        uint bits = ~(uint)(k >> 32);
        if (bits >= cutv) { int p = atomicAdd(&scnt, 1); arr[p] = k; }
    }
    __syncthreads();
    int cc = scnt;
    int S = 1; while (S < cc) S <<= 1; if (S < 2) S = 2;
    for (int i = cc + tid; i < S; i += 256) arr[i] = ~0ull;
    __syncthreads();

    for (int k = 2; k <= S; k <<= 1) {
        for (int jj = k >> 1; jj > 0; jj >>= 1) {
            for (int i = tid; i < S; i += 256) {
                int ixj = i ^ jj;
                if (ixj > i) {
                    ull a = arr[i], b2 = arr[ixj];
                    bool up = ((i & k) == 0);
                    if ((a > b2) == up) { arr[i] = b2; arr[ixj] = a; }
                }
            }
            __syncthreads();
        }
    }

    if (tid < KTOP) {
        float val = 0.f; uint n = 0;
        if (tid < cc) {
            ull kk = arr[tid];
            val = __uint_as_float(~(uint)(kk >> 32));
            n = (uint)(kk & 0xFFFFFFFFu);
        }
        sv[tid] = val;
        float4 l = reinterpret_cast<const float4*>(loc)[(size_t)bimg * NN + n];
        float4 p = reinterpret_cast<const float4*>(priors)[n];
        float cx = __fadd_rn(__fmul_rn(__fmul_rn(l.x, 0.1f), p.z), p.x);
        float cy = __fadd_rn(__fmul_rn(__fmul_rn(l.y, 0.1f), p.w), p.y);
        float w  = __fmul_rn(expf(__fmul_rn(l.z, 0.2f)), p.z);
        float h  = __fmul_rn(expf(__fmul_rn(l.w, 0.2f)), p.w);
        bx[tid][0] = __fsub_rn(cx, __fmul_rn(w, 0.5f));
        bx[tid][1] = __fsub_rn(cy, __fmul_rn(h, 0.5f));
        bx[tid][2] = __fadd_rn(cx, __fmul_rn(w, 0.5f));
        bx[tid][3] = __fadd_rn(cy, __fmul_rn(h, 0.5f));
    }
    __syncthreads();

    if (tid < KTOP) {
        float x1 = bx[tid][0], y1 = bx[tid][1], x2 = bx[tid][2], y2 = bx[tid][3];
        float ai = __fmul_rn(fmaxf(__fsub_rn(x2, x1), 0.f), fmaxf(__fsub_rn(y2, y1), 0.f));
        ull lo = 0, hi = 0;
        for (int jj = 0; jj < KTOP; ++jj) {
            float jx1 = bx[jj][0], jy1 = bx[jj][1], jx2 = bx[jj][2], jy2 = bx[jj][3];
            float iw = fmaxf(__fsub_rn(fminf(x2, jx2), fmaxf(x1, jx1)), 0.f);
            float ih = fmaxf(__fsub_rn(fminf(y2, jy2), fmaxf(y1, jy1)), 0.f);
            float inter = __fmul_rn(iw, ih);
            float aj = __fmul_rn(fmaxf(__fsub_rn(jx2, jx1), 0.f), fmaxf(__fsub_rn(jy2, jy1), 0.f));
            float denom = __fadd_rn(__fsub_rn(__fadd_rn(ai, aj), inter), 1e-8f);
            float iou = __fdiv_rn(inter, denom);
            if (iou > 0.45f) { if (jj < 64) lo |= (1ull << jj); else hi |= (1ull << (jj - 64)); }
        }
        mlo[tid] = lo; mhi[tid] = hi;
    }
    __syncthreads();

    if (tid == 0) {
        ull klo = 0, khi = 0;
        for (int i = 0; i < KTOP; ++i) {
            ull sup = (mlo[i] & klo) | (mhi[i] & khi);
            bool kp = (sv[i] > 0.f) && (sup == 0ull);
            if (kp) { if (i < 64) klo |= (1ull << i); else khi |= (1ull << (i - 64)); }
        }
        keeplo = klo; keephi = khi;
    }
    __syncthreads();

    if (tid < KTOP) {
        bool kp = (tid < 64) ? ((keeplo >> tid) & 1ull) : ((keephi >> (tid - 64)) & 1ull);
        size_t obase = (size_t)bc * KTOP + tid;
        nms_scores[obase] = kp ? sv[tid] : 0.f;
        float4 o; o.x = bx[tid][0]; o.y = bx[tid][1]; o.z = bx[tid][2]; o.w = bx[tid][3];
        reinterpret_cast<float4*>(nms_boxes)[obase] = o;
    }
}

// ---- final top-100, stage A: per-(image,chunk) top-100 of 1000 ----
__global__ __launch_bounds__(256) void final_partial_kernel(const float* __restrict__ nms_scores,
                                                            ull* __restrict__ fkeys) {
    int blk = blockIdx.x;             // b*FCH + ch
    int b = blk / FCH, ch = blk % FCH;
    __shared__ ull arr[FPAD];         // 8 KB
    int tid = threadIdx.x;
    const float* srow = nms_scores + (size_t)b * (CM1 * KTOP) + ch * FCHN;
    for (int i = tid; i < FPAD; i += 256) {
        ull key;
        if (i < FCHN) {
            float s = srow[i];
            uint bits = (s > 0.f) ? __float_as_uint(s) : 0u;
            key = (((ull)(~bits)) << 32) | (uint)(ch * FCHN + i);   // global per-image idx
        } else key = ~0ull;
        arr[i] = key;
    }
    __syncthreads();
    for (int k = 2; k <= FPAD; k <<= 1) {
        for (int jj = k >> 1; jj > 0; jj >>= 1) {
            for (int i = tid; i < FPAD; i += 256) {
                int ixj = i ^ jj;
                if (ixj > i) {
                    ull a = arr[i], b2 = arr[ixj];
                    bool up = ((i & k) == 0);
                    if ((a > b2) == up) { arr[i] = b2; arr[ixj] = a; }
                }
            }
            __syncthreads();
        }
    }
    if (tid < KTOP)
        fkeys[(size_t)b * (FCH * KTOP) + ch * KTOP + tid] = arr[tid];
}

// ---- final top-100, stage B: merge 8x100 -> exact top-100, gather ----
__global__ __launch_bounds__(256) void final_merge_kernel(const ull* __restrict__ fkeys,
                                                          const float* __restrict__ nms_boxes,
                                                          float* __restrict__ out) {
    int b = blockIdx.x;
    __shared__ ull arr[FPAD];         // 8 KB
    int tid = threadIdx.x;
    const ull* krow = fkeys + (size_t)b * (FCH * KTOP);
    for (int i = tid; i < FPAD; i += 256)
        arr[i] = (i < FCH * KTOP) ? krow[i] : ~0ull;
    __syncthreads();
    for (int k = 2; k <= FPAD; k <<= 1) {
        for (int jj = k >> 1; jj > 0; jj >>= 1) {
            for (int i = tid; i < FPAD; i += 256) {
                int ixj = i ^ jj;
                if (ixj > i) {
                    ull a = arr[i], b2 = arr[ixj];
                    bool up = ((i & k) == 0);
                    if ((a > b2) == up) { arr[i] = b2; arr[ixj] = a; }
                }
            }
            __syncthreads();
        }
    }
    if (tid < MAXDET) {
        ull kk = arr[tid];
        uint hb = (uint)(kk >> 32);
        uint idx = (uint)(kk & 0xFFFFFFFFu);
        float val = __uint_as_float(~hb);     // zeros decode to 0.0f
        float4 b4 = reinterpret_cast<const float4*>(nms_boxes)[(size_t)b * (CM1 * KTOP) + idx];
        reinterpret_cast<float4*>(out)[(size_t)b * MAXDET + tid] = b4;
        out[BB * MAXDET * 4 + b * MAXDET + tid] = val;
        out[BB * MAXDET * 5 + b * MAXDET + tid] = (float)(idx / KTOP + 1);
    }
}

extern "C" void kernel_launch(void* const* d_in, const int* in_sizes, int n_in,
                              void* d_out, int out_size, void* d_ws, size_t ws_size,
                              hipStream_t stream) {
    const float* loc    = (const float*)d_in[0];
    const float* conf   = (const float*)d_in[1];
    const float* priors = (const float*)d_in[2];
    float* out = (float*)d_out;

    // workspace layout (16B-aligned chunks)
    char* ws = (char*)d_ws;
    float* nms_scores = (float*)ws;                                        // 1.02 MB
    float* nms_boxes  = nms_scores + (size_t)BB * CM1 * KTOP;              // 4.1 MB
    ull*   cand       = (ull*)(nms_boxes + (size_t)BB * CM1 * KTOP * 4);   // 41.9 MB
    float2* mxs       = (float2*)(cand + (size_t)BB * CM1 * CAP2);         // 6.3 MB
    ull*   fkeys      = (ull*)(mxs + (size_t)BB * NN);                     // 0.2 MB
    uint*  histg      = (uint*)(fkeys + (size_t)BB * FCH * KTOP);          // 13.8 MB
    uint*  cuts       = histg + (size_t)BB * BPI * HWORDS;                 // 2560
    uint*  flags      = cuts + (size_t)BB * CM1;                           // 2560
    uint*  ccnt       = flags + (size_t)BB * CM1;                          // 2560
    uint*  ovf        = ccnt + (size_t)BB * CM1;                           // 2560

    // zero ccnt + ovf (contiguous 5120 words) with our own kernel — NOT hipMemsetAsync:
    // the runtime fill path costs ~147us per invocation regardless of size (round 9/10 profile)
    zero_kernel<<<(BB * CM1 * 2 + 255) / 256, 256, 0, stream>>>(ccnt, BB * CM1 * 2);

    softmax_hist_kernel<<<BB * BPI, 256, 0, stream>>>(conf, histg, mxs, cand, ccnt, ovf);
    cut_kernel<<<BB * CM1, 64, 0, stream>>>(histg, ccnt, ovf, cuts, flags);
    fallback_kernel<<<BB * CM1, 256, 0, stream>>>(conf, mxs, cuts, flags, cand, ccnt);
    nms_kernel<<<BB * CM1, 256, 0, stream>>>(cand, ccnt, cuts, loc, priors, nms_scores, nms_boxes);
    final_partial_kernel<<<BB * FCH, 256, 0, stream>>>(nms_scores, fkeys);
    final_merge_kernel<<<BB, 256, 0, stream>>>(fkeys, nms_boxes, out);
}